// Round 6
// baseline (128.885 us; speedup 1.0000x reference)
//
#include <hip/hip_runtime.h>
#include <cstdint>
#include <cstddef>

#define L_SEQ 2048
#define E_DIM 512
#define B_SZ 2
#define WIN 64
#define SCALE_QK 0.044194173824159216f  // 1/sqrt(512)

typedef __attribute__((ext_vector_type(8))) short short8;
typedef __attribute__((ext_vector_type(4))) float floatx4;

__device__ __forceinline__ unsigned short f2bf(float f) {
    unsigned int u = __float_as_uint(f);
    u += 0x7FFFu + ((u >> 16) & 1u);
    return (unsigned short)(u >> 16);
}

// ---------------- fp32 -> bf16 conversion of x, Wq, Wk, Wv ----------------
__global__ __launch_bounds__(256) void cvt_kernel(
    const float* __restrict__ x, const float* __restrict__ wq,
    const float* __restrict__ wk, const float* __restrict__ wv,
    unsigned short* __restrict__ xb, unsigned short* __restrict__ wb)
{
    long i = (long)blockIdx.x * 256 + threadIdx.x;   // 0 .. 720895
    const float* src;
    unsigned short* dst;
    long off;
    if (i < 524288) {
        src = x; dst = xb; off = i;
    } else {
        long j = i - 524288;
        int w = (int)(j >> 16);
        off = j & 65535;
        src = (w == 0) ? wq : ((w == 1) ? wk : wv);
        dst = wb + (long)w * 262144;
    }
    float4 f = ((const float4*)src)[off];
    ushort4 o;
    o.x = f2bf(f.x); o.y = f2bf(f.y); o.z = f2bf(f.z); o.w = f2bf(f.w);
    ((ushort4*)dst)[off] = o;
}

// ---------------- QKV projection: barrier-free, W-tile-in-LDS, direct X frags ----------------
// C[m,n] = sum_k X[m,k] W[n,k] + bias[n].  One barrier per block (after W staging).
// Operand-swap epilogue: z<2 -> mfma(W,X): D col=m, rows=n contiguous -> ushort4 q/k stores.
//                        z==2 -> mfma(X,W): D col=n, rows=m contiguous -> ushort4 vt stores.
// Block: 256 thr (4 waves). Wave w: m-rows [m0+32w, m0+32w+32), n-cols [n0, n0+32).
// Grid (32,16,3) = 1536 blocks, 32.5 KB LDS -> 4 blocks/CU = 16 waves/CU.
#define WLD 520   // W LDS row stride (bf16): +8 pad; 1040 B row, 16 B aligned
__global__ __launch_bounds__(256) void qkv_gemm(
    const unsigned short* __restrict__ xb,   // 4096 x 512 bf16
    const unsigned short* __restrict__ wb,   // 3 x (512 x 512) bf16, (N,K)
    const float* __restrict__ bq, const float* __restrict__ bk, const float* __restrict__ bv,
    unsigned short* __restrict__ q, unsigned short* __restrict__ k,
    unsigned short* __restrict__ vt)
{
    __shared__ __align__(16) unsigned short Ws[32 * WLD];   // 33280 B

    const int t = threadIdx.x;
    const int w = t >> 6, l = t & 63;
    const int fr = l & 15, fq = l >> 4;
    const int m0 = blockIdx.x * 128, n0 = blockIdx.y * 32, z = blockIdx.z;
    const unsigned short* W = wb + (size_t)z * 262144;
    const float* bias = (z == 0) ? bq : ((z == 1) ? bk : bv);

    // stage W tile: 32 rows x 512 cols. thread t: row t>>3, col base (t&7)*64
    {
        const int r = t >> 3, cb = (t & 7) * 64;
        const unsigned short* src = W + (size_t)(n0 + r) * 512 + cb;
        unsigned short* dst = Ws + r * WLD + cb;
#pragma unroll
        for (int s = 0; s < 8; s++)
            *(uint4*)(dst + s * 8) = *(const uint4*)(src + s * 8);
    }
    __syncthreads();

    const int mb = m0 + w * 32;
    const unsigned short* xr0 = xb + (size_t)(mb + fr) * 512 + fq * 8;        // m-tile 0
    const unsigned short* xr1 = xb + (size_t)(mb + 16 + fr) * 512 + fq * 8;   // m-tile 1
    const unsigned short* wr0 = Ws + (size_t)fr * WLD + fq * 8;               // n-tile 0
    const unsigned short* wr1 = Ws + (size_t)(16 + fr) * WLD + fq * 8;        // n-tile 1

    floatx4 acc[2][2] = {};
    if (z < 2) {
#pragma unroll
        for (int ks = 0; ks < 16; ks++) {
            short8 x0 = *(const short8*)(xr0 + ks * 32);
            short8 x1 = *(const short8*)(xr1 + ks * 32);
            short8 w0 = *(const short8*)(wr0 + ks * 32);
            short8 w1 = *(const short8*)(wr1 + ks * 32);
            acc[0][0] = __builtin_amdgcn_mfma_f32_16x16x32_bf16(w0, x0, acc[0][0], 0, 0, 0);
            acc[0][1] = __builtin_amdgcn_mfma_f32_16x16x32_bf16(w0, x1, acc[0][1], 0, 0, 0);
            acc[1][0] = __builtin_amdgcn_mfma_f32_16x16x32_bf16(w1, x0, acc[1][0], 0, 0, 0);
            acc[1][1] = __builtin_amdgcn_mfma_f32_16x16x32_bf16(w1, x1, acc[1][1], 0, 0, 0);
        }
        // D col = m (= fr within m-tile), rows = n (= fq*4+r contiguous)
        unsigned short* out = (z == 0) ? q : k;
#pragma unroll
        for (int nt = 0; nt < 2; nt++) {
            int n = n0 + nt * 16 + fq * 4;
            float b0 = bias[n], b1 = bias[n + 1], b2 = bias[n + 2], b3 = bias[n + 3];
#pragma unroll
            for (int mt = 0; mt < 2; mt++) {
                int m = mb + mt * 16 + fr;
                ushort4 pk;
                pk.x = f2bf(acc[nt][mt][0] + b0);
                pk.y = f2bf(acc[nt][mt][1] + b1);
                pk.z = f2bf(acc[nt][mt][2] + b2);
                pk.w = f2bf(acc[nt][mt][3] + b3);
                *(ushort4*)&out[(size_t)m * 512 + n] = pk;
            }
        }
    } else {
#pragma unroll
        for (int ks = 0; ks < 16; ks++) {
            short8 x0 = *(const short8*)(xr0 + ks * 32);
            short8 x1 = *(const short8*)(xr1 + ks * 32);
            short8 w0 = *(const short8*)(wr0 + ks * 32);
            short8 w1 = *(const short8*)(wr1 + ks * 32);
            acc[0][0] = __builtin_amdgcn_mfma_f32_16x16x32_bf16(x0, w0, acc[0][0], 0, 0, 0);
            acc[0][1] = __builtin_amdgcn_mfma_f32_16x16x32_bf16(x0, w1, acc[0][1], 0, 0, 0);
            acc[1][0] = __builtin_amdgcn_mfma_f32_16x16x32_bf16(x1, w0, acc[1][0], 0, 0, 0);
            acc[1][1] = __builtin_amdgcn_mfma_f32_16x16x32_bf16(x1, w1, acc[1][1], 0, 0, 0);
        }
        // D col = n (= fr within n-tile), rows = m (= fq*4+r contiguous)
#pragma unroll
        for (int mt = 0; mt < 2; mt++) {
            int m = mb + mt * 16 + fq * 4;
#pragma unroll
            for (int nt = 0; nt < 2; nt++) {
                int n = n0 + nt * 16 + fr;
                float bvv = bias[n];
                ushort4 pk;
                pk.x = f2bf(acc[mt][nt][0] + bvv);
                pk.y = f2bf(acc[mt][nt][1] + bvv);
                pk.z = f2bf(acc[mt][nt][2] + bvv);
                pk.w = f2bf(acc[mt][nt][3] + bvv);
                *(ushort4*)&vt[(size_t)n * 4096 + m] = pk;
            }
        }
    }
}

// ---------------- scores: S[16x16] per one-wave block, direct frag loads ----------------
// grid (128 Qtiles, 9 ntiles, 2 b), 64 threads. S fp32 [4096][160], cols 0..143 written.
__global__ __launch_bounds__(64) void scores_kernel(
    const unsigned short* __restrict__ qb, const unsigned short* __restrict__ kb,
    float* __restrict__ S)
{
    const int l = threadIdx.x;
    const int fr = l & 15, fq = l >> 4;
    const int Q0 = blockIdx.x * 16;
    const int nt = blockIdx.y;
    const int b  = blockIdx.z;
    const int R0 = Q0 - WIN;
    const int tok = R0 + nt * 16 + fr;
    const bool kvalid = (tok >= 0) && (tok < L_SEQ);

    const unsigned short* qrow = qb + (size_t)(b * L_SEQ + Q0 + fr) * 512 + fq * 8;
    const unsigned short* krow = kb + (size_t)(b * L_SEQ) * 512 + (size_t)tok * 512 + fq * 8;

    floatx4 acc = {};
#pragma unroll
    for (int ks = 0; ks < 16; ks++) {
        short8 a = *(const short8*)(qrow + ks * 32);
        short8 bfr = {};
        if (kvalid) bfr = *(const short8*)(krow + ks * 32);
        acc = __builtin_amdgcn_mfma_f32_16x16x32_bf16(a, bfr, acc, 0, 0, 0);
    }

    const int jg = nt * 16 + fr;
    float* Srow = S + (size_t)(b * L_SEQ + Q0) * 160 + jg;
#pragma unroll
    for (int r = 0; r < 4; r++) {
        int qq = fq * 4 + r;
        bool valid = (jg >= qq) && (jg <= qq + 128) && kvalid;
        Srow[(size_t)qq * 160] = valid ? acc[r] * SCALE_QK : -1e30f;
    }
}

// ---------------- pv (fused softmax): out[16q x 32e] per one-wave block ----------------
// grid (128 Qtiles, 16 e-pairs, 2 b), 64 threads. Reads raw S, computes softmax
// in-register (4 lanes per q-row via shfl_xor 16/32), builds bf16 A-frags, MFMA vs vT.
__global__ __launch_bounds__(64) void pv_kernel(
    const float* __restrict__ S, const unsigned short* __restrict__ vt,
    float* __restrict__ out)
{
    const int l = threadIdx.x;
    const int fr = l & 15, fq = l >> 4;
    const int Q0 = blockIdx.x * 16;
    const int EC = blockIdx.y * 32;
    const int b  = blockIdx.z;
    const int R0 = Q0 - WIN;

    // lane covers S row (Q0+fr), cols fq*8 + ks*32 + j  (ks<5, j<8)
    const float* Srow = S + (size_t)(b * L_SEQ + Q0 + fr) * 160 + fq * 8;
    float sv[5][8];
#pragma unroll
    for (int ks = 0; ks < 5; ks++) {
        float4 u0 = *(const float4*)(Srow + ks * 32);
        float4 u1 = *(const float4*)(Srow + ks * 32 + 4);
        sv[ks][0] = u0.x; sv[ks][1] = u0.y; sv[ks][2] = u0.z; sv[ks][3] = u0.w;
        sv[ks][4] = u1.x; sv[ks][5] = u1.y; sv[ks][6] = u1.z; sv[ks][7] = u1.w;
    }
    if (fq >= 2) {                    // cols 144..159: unwritten pad
#pragma unroll
        for (int j = 0; j < 8; j++) sv[4][j] = -1e30f;
    }
    float m = -1e30f;
#pragma unroll
    for (int ks = 0; ks < 5; ks++)
#pragma unroll
        for (int j = 0; j < 8; j++) m = fmaxf(m, sv[ks][j]);
    m = fmaxf(m, __shfl_xor(m, 16));
    m = fmaxf(m, __shfl_xor(m, 32));
    float sum = 0.f;
#pragma unroll
    for (int ks = 0; ks < 5; ks++)
#pragma unroll
        for (int j = 0; j < 8; j++) { float e = __expf(sv[ks][j] - m); sv[ks][j] = e; sum += e; }
    sum += __shfl_xor(sum, 16);
    sum += __shfl_xor(sum, 32);
    float inv = 1.f / sum;

    short8 a[5];
#pragma unroll
    for (int ks = 0; ks < 5; ks++)
#pragma unroll
        for (int j = 0; j < 8; j++) a[ks][j] = (short)f2bf(sv[ks][j] * inv);

    floatx4 oa[2] = {};
#pragma unroll
    for (int ks = 0; ks < 5; ks++) {
        int tok0 = R0 + ks * 32 + fq * 8;                 // mod-8 aligned granule
        bool tv = (tok0 >= 0) && (tok0 < L_SEQ);
#pragma unroll
        for (int et = 0; et < 2; et++) {
            short8 bfr = {};
            if (tv) bfr = *(const short8*)&vt[(size_t)(EC + et * 16 + fr) * 4096 + b * L_SEQ + tok0];
            oa[et] = __builtin_amdgcn_mfma_f32_16x16x32_bf16(a[ks], bfr, oa[et], 0, 0, 0);
        }
    }

    float* op = out + (size_t)b * L_SEQ * E_DIM;
#pragma unroll
    for (int et = 0; et < 2; et++)
#pragma unroll
        for (int r = 0; r < 4; r++)
            op[(size_t)(Q0 + fq * 4 + r) * 512 + EC + et * 16 + fr] = oa[et][r];
}

// ---------------- launch ----------------
extern "C" void kernel_launch(void* const* d_in, const int* in_sizes, int n_in,
                              void* d_out, int out_size, void* d_ws, size_t ws_size,
                              hipStream_t stream)
{
    const float* x  = (const float*)d_in[0];
    const float* Wq = (const float*)d_in[1];
    const float* bq = (const float*)d_in[2];
    const float* Wk = (const float*)d_in[3];
    const float* bk = (const float*)d_in[4];
    const float* Wv = (const float*)d_in[5];
    const float* bv = (const float*)d_in[6];
    float* out = (float*)d_out;

    char* ws = (char*)d_ws;
    unsigned short* qb = (unsigned short*)(ws);                  // 4 MB bf16 q
    unsigned short* kb = (unsigned short*)(ws + 4194304);        // 4 MB bf16 k
    unsigned short* vt = (unsigned short*)(ws + 8388608);        // 4 MB bf16 v^T [e][tok]
    unsigned short* xb = (unsigned short*)(ws + 12582912);       // 4 MB bf16 x
    unsigned short* wb = (unsigned short*)(ws + 16777216);       // 1.5 MB bf16 W
    float*          S  = (float*)(ws + 18350080);                // 2.62 MB fp32 [4096][160]

    cvt_kernel<<<2816, 256, 0, stream>>>(x, Wq, Wk, Wv, xb, wb);
    qkv_gemm<<<dim3(32, 16, 3), 256, 0, stream>>>(xb, wb, bq, bk, bv, qb, kb, vt);
    scores_kernel<<<dim3(128, 9, 2), 64, 0, stream>>>(qb, kb, S);
    pv_kernel<<<dim3(128, 16, 2), 64, 0, stream>>>(S, vt, out);
}

// Round 7
// 110.469 us; speedup vs baseline: 1.1667x; 1.1667x over previous
//
#include <hip/hip_runtime.h>
#include <cstdint>
#include <cstddef>

#define L_SEQ 2048
#define E_DIM 512
#define B_SZ 2
#define WIN 64
#define SCALE_QK 0.044194173824159216f  // 1/sqrt(512)

typedef __attribute__((ext_vector_type(8))) short short8;
typedef __attribute__((ext_vector_type(4))) float floatx4;

__device__ __forceinline__ unsigned short f2bf(float f) {
    unsigned int u = __float_as_uint(f);
    u += 0x7FFFu + ((u >> 16) & 1u);
    return (unsigned short)(u >> 16);
}

// ---------------- fp32 -> bf16 conversion of x, Wq, Wk, Wv ----------------
__global__ __launch_bounds__(256) void cvt_kernel(
    const float* __restrict__ x, const float* __restrict__ wq,
    const float* __restrict__ wk, const float* __restrict__ wv,
    unsigned short* __restrict__ xb, unsigned short* __restrict__ wb)
{
    long i = (long)blockIdx.x * 256 + threadIdx.x;   // 0 .. 720895
    const float* src;
    unsigned short* dst;
    long off;
    if (i < 524288) {
        src = x; dst = xb; off = i;
    } else {
        long j = i - 524288;
        int w = (int)(j >> 16);
        off = j & 65535;
        src = (w == 0) ? wq : ((w == 1) ? wk : wv);
        dst = wb + (long)w * 262144;
    }
    float4 f = ((const float4*)src)[off];
    ushort4 o;
    o.x = f2bf(f.x); o.y = f2bf(f.y); o.z = f2bf(f.z); o.w = f2bf(f.w);
    ((ushort4*)dst)[off] = o;
}

// ---------------- QKV projection: 64x64 tile, BK=64, reg double-buffer (R5 winner) ----------------
// C[m,n] = sum_k X[m,k] W[n,k] + bias[n].  Outputs bf16, coalesced via LDS transpose.
// z==0 -> q[m][n], z==1 -> k[m][n], z==2 -> vT[n][m] (token-contiguous rows).
// grid (64,8,3) = 1536 blocks = 6 blocks/CU.
#define ALD 72   // LDS row stride (bf16): 36 dw -> 2-way conflicts only per 16-lane phase
__global__ __launch_bounds__(256) void qkv_gemm(
    const unsigned short* __restrict__ xb,   // 4096 x 512
    const unsigned short* __restrict__ wb,   // 3 x (512 x 512), (N,K)
    const float* __restrict__ bq, const float* __restrict__ bk, const float* __restrict__ bv,
    unsigned short* __restrict__ q, unsigned short* __restrict__ k,
    unsigned short* __restrict__ vt)
{
    __shared__ __align__(16) unsigned short As[64 * ALD];   // 9216 B (aliased by epilogue)
    __shared__ __align__(16) unsigned short Bs[64 * ALD];

    const int t = threadIdx.x;
    const int w = t >> 6, l = t & 63;
    const int m0 = blockIdx.x * 64, n0 = blockIdx.y * 64, z = blockIdx.z;
    const unsigned short* W = wb + (size_t)z * 262144;
    const float* bias = (z == 0) ? bq : ((z == 1) ? bk : bv);

    floatx4 acc[2][2] = {};
    const int wm = (w >> 1) * 32, wn = (w & 1) * 32;
    const int fr = l & 15, fq = l >> 4, fk = fq * 8;

    const int srow = t >> 2, scol = (t & 3) * 16;
    const unsigned short* gA = xb + (size_t)(m0 + srow) * 512 + scol;
    const unsigned short* gB = W  + (size_t)(n0 + srow) * 512 + scol;

    uint4 ra0 = *(const uint4*)(gA);     uint4 ra1 = *(const uint4*)(gA + 8);
    uint4 rb0 = *(const uint4*)(gB);     uint4 rb1 = *(const uint4*)(gB + 8);

    for (int it = 0; it < 8; it++) {
        *(uint4*)&As[srow * ALD + scol]     = ra0;
        *(uint4*)&As[srow * ALD + scol + 8] = ra1;
        *(uint4*)&Bs[srow * ALD + scol]     = rb0;
        *(uint4*)&Bs[srow * ALD + scol + 8] = rb1;
        __syncthreads();
        if (it < 7) {                       // prefetch next K-slice; overlaps compute below
            int kk = (it + 1) * 64;
            ra0 = *(const uint4*)(gA + kk); ra1 = *(const uint4*)(gA + kk + 8);
            rb0 = *(const uint4*)(gB + kk); rb1 = *(const uint4*)(gB + kk + 8);
        }
        short8 a[2][2], bf[2][2];
#pragma unroll
        for (int i = 0; i < 2; i++)
#pragma unroll
            for (int kh = 0; kh < 2; kh++)
                a[i][kh] = *(const short8*)&As[(wm + i * 16 + fr) * ALD + kh * 32 + fk];
#pragma unroll
        for (int j = 0; j < 2; j++)
#pragma unroll
            for (int kh = 0; kh < 2; kh++)
                bf[j][kh] = *(const short8*)&Bs[(wn + j * 16 + fr) * ALD + kh * 32 + fk];
#pragma unroll
        for (int kh = 0; kh < 2; kh++)
#pragma unroll
            for (int i = 0; i < 2; i++)
#pragma unroll
                for (int j = 0; j < 2; j++)
                    acc[i][j] = __builtin_amdgcn_mfma_f32_16x16x32_bf16(a[i][kh], bf[j][kh], acc[i][j], 0, 0, 0);
        __syncthreads();
    }

    // epilogue: frags (C/D: col=lane&15, row=(lane>>4)*4+reg) -> LDS tile -> coalesced stores
    unsigned short* Tl = As;   // 64 x ALD alias
    float bv_[2];
#pragma unroll
    for (int j = 0; j < 2; j++) bv_[j] = bias[n0 + wn + j * 16 + fr];

    if (z < 2) {
#pragma unroll
        for (int i = 0; i < 2; i++)
#pragma unroll
            for (int j = 0; j < 2; j++)
#pragma unroll
                for (int r = 0; r < 4; r++)
                    Tl[(wm + i * 16 + fq * 4 + r) * ALD + wn + j * 16 + fr] =
                        f2bf(acc[i][j][r] + bv_[j]);
    } else {
#pragma unroll
        for (int i = 0; i < 2; i++)
#pragma unroll
            for (int j = 0; j < 2; j++)
#pragma unroll
                for (int r = 0; r < 4; r++)
                    Tl[(wn + j * 16 + fr) * ALD + wm + i * 16 + fq * 4 + r] =
                        f2bf(acc[i][j][r] + bv_[j]);
    }
    __syncthreads();

    const int tr = t >> 2, tc = (t & 3) * 16;
    uint4 v0 = *(const uint4*)&Tl[tr * ALD + tc];
    uint4 v1 = *(const uint4*)&Tl[tr * ALD + tc + 8];
    if (z < 2) {
        unsigned short* out = (z == 0) ? q : k;
        *(uint4*)&out[(size_t)(m0 + tr) * 512 + n0 + tc]     = v0;
        *(uint4*)&out[(size_t)(m0 + tr) * 512 + n0 + tc + 8] = v1;
    } else {
        *(uint4*)&vt[(size_t)(n0 + tr) * 4096 + m0 + tc]     = v0;
        *(uint4*)&vt[(size_t)(n0 + tr) * 4096 + m0 + tc + 8] = v1;
    }
}

// ---------------- scores: S[16x16] per one-wave block, direct frag loads ----------------
// grid (128 Qtiles, 9 ntiles, 2 b), 64 threads. S fp32 [4096][160], cols 0..143 written.
__global__ __launch_bounds__(64) void scores_kernel(
    const unsigned short* __restrict__ qb, const unsigned short* __restrict__ kb,
    float* __restrict__ S)
{
    const int l = threadIdx.x;
    const int fr = l & 15, fq = l >> 4;
    const int Q0 = blockIdx.x * 16;
    const int nt = blockIdx.y;
    const int b  = blockIdx.z;
    const int R0 = Q0 - WIN;
    const int tok = R0 + nt * 16 + fr;
    const bool kvalid = (tok >= 0) && (tok < L_SEQ);

    const unsigned short* qrow = qb + (size_t)(b * L_SEQ + Q0 + fr) * 512 + fq * 8;
    const unsigned short* krow = kb + (size_t)(b * L_SEQ) * 512 + (size_t)tok * 512 + fq * 8;

    floatx4 acc = {};
#pragma unroll
    for (int ks = 0; ks < 16; ks++) {
        short8 a = *(const short8*)(qrow + ks * 32);
        short8 bfr = {};
        if (kvalid) bfr = *(const short8*)(krow + ks * 32);
        acc = __builtin_amdgcn_mfma_f32_16x16x32_bf16(a, bfr, acc, 0, 0, 0);
    }

    const int jg = nt * 16 + fr;
    float* Srow = S + (size_t)(b * L_SEQ + Q0) * 160 + jg;
#pragma unroll
    for (int r = 0; r < 4; r++) {
        int qq = fq * 4 + r;
        bool valid = (jg >= qq) && (jg <= qq + 128) && kvalid;
        Srow[(size_t)qq * 160] = valid ? acc[r] * SCALE_QK : -1e30f;
    }
}

// ---------------- pv (fused softmax): out[16q x 64e] per one-wave block ----------------
// grid (128 Qtiles, 8 e-quads, 2 b), 64 threads. Reads raw S, computes softmax
// in-register (4 lanes per q-row via shfl_xor 16/32), builds bf16 A-frags, MFMA vs vT.
__global__ __launch_bounds__(64) void pv_kernel(
    const float* __restrict__ S, const unsigned short* __restrict__ vt,
    float* __restrict__ out)
{
    const int l = threadIdx.x;
    const int fr = l & 15, fq = l >> 4;
    const int Q0 = blockIdx.x * 16;
    const int EC = blockIdx.y * 64;
    const int b  = blockIdx.z;
    const int R0 = Q0 - WIN;

    // lane covers S row (Q0+fr), cols fq*8 + ks*32 + j  (ks<5, j<8)
    const float* Srow = S + (size_t)(b * L_SEQ + Q0 + fr) * 160 + fq * 8;
    float sv[5][8];
#pragma unroll
    for (int ks = 0; ks < 5; ks++) {
        float4 u0 = *(const float4*)(Srow + ks * 32);
        float4 u1 = *(const float4*)(Srow + ks * 32 + 4);
        sv[ks][0] = u0.x; sv[ks][1] = u0.y; sv[ks][2] = u0.z; sv[ks][3] = u0.w;
        sv[ks][4] = u1.x; sv[ks][5] = u1.y; sv[ks][6] = u1.z; sv[ks][7] = u1.w;
    }
    if (fq >= 2) {                    // cols 144..159: unwritten pad
#pragma unroll
        for (int j = 0; j < 8; j++) sv[4][j] = -1e30f;
    }
    float m = -1e30f;
#pragma unroll
    for (int ks = 0; ks < 5; ks++)
#pragma unroll
        for (int j = 0; j < 8; j++) m = fmaxf(m, sv[ks][j]);
    m = fmaxf(m, __shfl_xor(m, 16));
    m = fmaxf(m, __shfl_xor(m, 32));
    float sum = 0.f;
#pragma unroll
    for (int ks = 0; ks < 5; ks++)
#pragma unroll
        for (int j = 0; j < 8; j++) { float e = __expf(sv[ks][j] - m); sv[ks][j] = e; sum += e; }
    sum += __shfl_xor(sum, 16);
    sum += __shfl_xor(sum, 32);
    float inv = 1.f / sum;

    short8 a[5];
#pragma unroll
    for (int ks = 0; ks < 5; ks++)
#pragma unroll
        for (int j = 0; j < 8; j++) a[ks][j] = (short)f2bf(sv[ks][j] * inv);

    floatx4 oa[4] = {};
#pragma unroll
    for (int ks = 0; ks < 5; ks++) {
        int tok0 = R0 + ks * 32 + fq * 8;                 // mod-8 aligned granule
        bool tv = (tok0 >= 0) && (tok0 < L_SEQ);
#pragma unroll
        for (int et = 0; et < 4; et++) {
            short8 bfr = {};
            if (tv) bfr = *(const short8*)&vt[(size_t)(EC + et * 16 + fr) * 4096 + b * L_SEQ + tok0];
            oa[et] = __builtin_amdgcn_mfma_f32_16x16x32_bf16(a[ks], bfr, oa[et], 0, 0, 0);
        }
    }

    float* op = out + (size_t)b * L_SEQ * E_DIM;
#pragma unroll
    for (int et = 0; et < 4; et++)
#pragma unroll
        for (int r = 0; r < 4; r++)
            op[(size_t)(Q0 + fq * 4 + r) * 512 + EC + et * 16 + fr] = oa[et][r];
}

// ---------------- launch ----------------
extern "C" void kernel_launch(void* const* d_in, const int* in_sizes, int n_in,
                              void* d_out, int out_size, void* d_ws, size_t ws_size,
                              hipStream_t stream)
{
    const float* x  = (const float*)d_in[0];
    const float* Wq = (const float*)d_in[1];
    const float* bq = (const float*)d_in[2];
    const float* Wk = (const float*)d_in[3];
    const float* bk = (const float*)d_in[4];
    const float* Wv = (const float*)d_in[5];
    const float* bv = (const float*)d_in[6];
    float* out = (float*)d_out;

    char* ws = (char*)d_ws;
    unsigned short* qb = (unsigned short*)(ws);                  // 4 MB bf16 q
    unsigned short* kb = (unsigned short*)(ws + 4194304);        // 4 MB bf16 k
    unsigned short* vt = (unsigned short*)(ws + 8388608);        // 4 MB bf16 v^T [e][tok]
    unsigned short* xb = (unsigned short*)(ws + 12582912);       // 4 MB bf16 x
    unsigned short* wb = (unsigned short*)(ws + 16777216);       // 1.5 MB bf16 W
    float*          S  = (float*)(ws + 18350080);                // 2.62 MB fp32 [4096][160]

    cvt_kernel<<<2816, 256, 0, stream>>>(x, Wq, Wk, Wv, xb, wb);
    qkv_gemm<<<dim3(64, 8, 3), 256, 0, stream>>>(xb, wb, bq, bk, bv, qb, kb, vt);
    scores_kernel<<<dim3(128, 9, 2), 64, 0, stream>>>(qb, kb, S);
    pv_kernel<<<dim3(128, 8, 2), 64, 0, stream>>>(S, vt, out);
}